// Round 4
// baseline (1830.971 us; speedup 1.0000x reference)
//
#include <hip/hip_runtime.h>
#include <math.h>

#define CC 20
#define BB 256
#define HH 10
#define SS 64
#define AA 16
#define HD 128
#define RH 64
#define CBR (CC*BB)      // 5120 rows
#define NSNN 15

// Replicate npy_logaddexpf(u, 0.f): float32 chain, expf/log1pf approximated
// at correctly-rounded level via f64 internals (beats OCML's 1-ulp).
__device__ __forceinline__ float softplus_np(float u) {
    if (u > 0.0f) {
        float ef = (float)exp((double)(-u));     // ~CR expf(-u)
        float l1 = (float)log1p((double)ef);     // ~CR log1pf
        return __fadd_rn(u, l1);                 // final f32 add, rounded
    } else if (u < 0.0f) {
        float ef = (float)exp((double)u);
        return (float)log1p((double)ef);
    } else {
        return 0.69314718055994530942f;          // x==y branch: ln2 in f32
    }
}

// One block = one rollout row (cb = c*B + b). 128 threads, thread j = hidden unit.
// float32 everywhere; every dot = single sequential-k fmaf chain (OpenBLAS sgemm
// order); every elementwise op separately rounded (no contraction).
__global__ __launch_bounds__(128) void world_kernel(
    int h,
    const float* __restrict__ current_state,   // [B,S]
    const float* __restrict__ actions,         // [C,B,H,A]
    const float* __restrict__ noise,           // [C,B,H,S]
    const float* __restrict__ Wse, const float* __restrict__ bse,
    const float* __restrict__ Wae, const float* __restrict__ bae,
    const float* __restrict__ W1,  const float* __restrict__ b1,
    const float* __restrict__ W2,  const float* __restrict__ b2,
    const float* __restrict__ Wdec, const float* __restrict__ bdec,
    const float* __restrict__ Wunc, const float* __restrict__ bunc,
    float* __restrict__ states)                // [H, CB, S]
{
    const int cb = blockIdx.x;
    const int j  = threadIdx.x;

    __shared__ float s_state[SS];
    __shared__ float s_sae[2*HD];
    __shared__ float s_spk[HD];
    __shared__ float s_mem2[HD];

    if (j < SS) {
        s_state[j] = (h == 0) ? current_state[(size_t)(cb % BB)*SS + j]
                              : states[((size_t)(h-1)*CBR + cb)*SS + j];
    }
    __syncthreads();

    // se = relu(state @ Wse + bse)   — sequential k, single fmaf chain
    float acc = 0.0f;
    for (int i = 0; i < SS; i++)
        acc = fmaf(s_state[i], Wse[i*HD + j], acc);
    float se = fmaxf(__fadd_rn(acc, bse[j]), 0.0f);

    // ae = relu(act @ Wae + bae)
    const float* act = actions + ((size_t)cb*HH + h)*AA;
    acc = 0.0f;
    for (int i = 0; i < AA; i++)
        acc = fmaf(act[i], Wae[i*HD + j], acc);
    float ae = fmaxf(__fadd_rn(acc, bae[j]), 0.0f);

    s_sae[j]      = se;
    s_sae[HD + j] = ae;
    __syncthreads();

    // cur = concat(se, ae) @ W1 + b1   (constant across SNN steps)
    acc = 0.0f;
    for (int i = 0; i < 2*HD; i++)
        acc = fmaf(s_sae[i], W1[i*HD + j], acc);
    const float cur = __fadd_rn(acc, b1[j]);

    // SNN scan, numpy elementwise rounding order:
    //   mem1 = (0.9f*mem1 + cur) - spike(mem1_old - 1)   (each op rounded)
    const float b2j = b2[j];
    float m1 = 0.0f, m2 = 0.0f;
    for (int t = 0; t < NSNN; t++) {
        float sp1old = (__fsub_rn(m1, 1.0f) > 0.0f) ? 1.0f : 0.0f;
        m1 = __fsub_rn(__fadd_rn(__fmul_rn(0.9f, m1), cur), sp1old);
        float spk = (__fsub_rn(m1, 1.0f) > 0.0f) ? 1.0f : 0.0f;
        __syncthreads();               // previous iteration's readers done
        s_spk[j] = spk;
        __syncthreads();
        float c2 = 0.0f;               // spk1 @ W2: sequential k incl. zeros
        for (int k = 0; k < HD; k++)
            c2 = fmaf(s_spk[k], W2[k*HD + j], c2);
        c2 = __fadd_rn(c2, b2j);
        float sp2old = (__fsub_rn(m2, 1.0f) > 0.0f) ? 1.0f : 0.0f;
        m2 = __fsub_rn(__fadd_rn(__fmul_rn(0.9f, m2), c2), sp2old);
    }
    s_mem2[j] = m2;
    __syncthreads();

    // decode + sample next state (threads 0..63 do both mean and unc)
    if (j < SS) {
        float cm = 0.0f, cu = 0.0f;
        for (int n = 0; n < HD; n++) {
            cm = fmaf(s_mem2[n], Wdec[n*SS + j], cm);
            cu = fmaf(s_mem2[n], Wunc[n*SS + j], cu);
        }
        float mean = __fadd_rn(cm, bdec[j]);
        float u    = __fadd_rn(cu, bunc[j]);
        float var  = softplus_np(u);
        float sv   = sqrtf(__fadd_rn(var, 1e-8f));   // sqrtf is CR both sides
        float nz   = noise[((size_t)cb*HH + h)*SS + j];
        states[((size_t)h*CBR + cb)*SS + j] = __fadd_rn(mean, __fmul_rn(nz, sv));
    }
}

// One block = one row (cb), 64 threads = Rh columns; loops over H, f32 sum.
__global__ __launch_bounds__(64) void reward_kernel(
    const float* __restrict__ states,    // [H, CB, S]
    const float* __restrict__ actions,   // [C,B,H,A]
    const float* __restrict__ Wr1, const float* __restrict__ br1,
    const float* __restrict__ Wr2, const float* __restrict__ br2,
    const float* __restrict__ Wr3, const float* __restrict__ br3,
    float* __restrict__ cum)             // [CB]
{
    const int cb = blockIdx.x;
    const int j  = threadIdx.x;
    __shared__ float s_x[SS + AA];
    __shared__ float s_h[RH];
    __shared__ float s_h2[RH];

    float total = 0.0f;
    for (int h = 0; h < HH; h++) {
        __syncthreads();
        s_x[j] = states[((size_t)h*CBR + cb)*SS + j];
        if (j < AA) s_x[SS + j] = actions[((size_t)cb*HH + h)*AA + j];
        __syncthreads();

        float a = 0.0f;
        for (int i = 0; i < SS + AA; i++)
            a = fmaf(s_x[i], Wr1[i*RH + j], a);
        float hv = fmaxf(__fadd_rn(a, br1[j]), 0.0f);
        s_h[j] = hv;
        __syncthreads();

        float g = 0.0f;
        for (int i = 0; i < RH; i++)
            g = fmaf(s_h[i], Wr2[i*RH + j], g);
        float h2v = fmaxf(__fadd_rn(g, br2[j]), 0.0f);
        s_h2[j] = h2v;
        __syncthreads();

        if (j == 0) {
            float r = 0.0f;                       // h2 @ Wr3: sequential k
            for (int k = 0; k < RH; k++)
                r = fmaf(s_h2[k], Wr3[k], r);
            r = __fadd_rn(r, br3[0]);
            total = __fadd_rn(total, r);          // sequential sum over h
        }
    }
    if (j == 0) cum[cb] = total;
}

// One block per batch element b: f32 argmax over C (strict > = first max),
// gather best action.
__global__ __launch_bounds__(64) void select_kernel(
    const float* __restrict__ cum,      // [CB], cb = c*B + b
    const float* __restrict__ actions,  // [C,B,H,A]
    float* __restrict__ out)            // [B*H*A] actions then [B] values
{
    const int b = blockIdx.x;
    const int j = threadIdx.x;
    __shared__ int s_c;

    if (j == 0) {
        float best = cum[b];            // c = 0
        int bc = 0;
        for (int c = 1; c < CC; c++) {
            float v = cum[(size_t)c*BB + b];
            if (v > best) { best = v; bc = c; }
        }
        s_c = bc;
        out[(size_t)BB*HH*AA + b] = best;
    }
    __syncthreads();
    const int bc = s_c;
    const float* src = actions + ((size_t)bc*BB + b)*HH*AA;
    for (int i = j; i < HH*AA; i += 64) out[(size_t)b*HH*AA + i] = src[i];
}

extern "C" void kernel_launch(void* const* d_in, const int* in_sizes, int n_in,
                              void* d_out, int out_size, void* d_ws, size_t ws_size,
                              hipStream_t stream)
{
    const float* current_state = (const float*)d_in[0];
    const float* actions = (const float*)d_in[1];
    const float* noise   = (const float*)d_in[2];
    const float* Wse = (const float*)d_in[3];
    const float* bse = (const float*)d_in[4];
    const float* Wae = (const float*)d_in[5];
    const float* bae = (const float*)d_in[6];
    const float* W1  = (const float*)d_in[7];
    const float* b1  = (const float*)d_in[8];
    const float* W2  = (const float*)d_in[9];
    const float* b2  = (const float*)d_in[10];
    const float* Wdec = (const float*)d_in[11];
    const float* bdec = (const float*)d_in[12];
    const float* Wunc = (const float*)d_in[13];
    const float* bunc = (const float*)d_in[14];
    const float* Wr1 = (const float*)d_in[15];
    const float* br1 = (const float*)d_in[16];
    const float* Wr2 = (const float*)d_in[17];
    const float* br2 = (const float*)d_in[18];
    const float* Wr3 = (const float*)d_in[19];
    const float* br3 = (const float*)d_in[20];

    float* states = (float*)d_ws;                       // 10*5120*64 f32 = 13.1 MB
    float* cum    = states + (size_t)HH*CBR*SS;         // 5120 f32

    for (int h = 0; h < HH; h++) {
        world_kernel<<<CBR, HD, 0, stream>>>(h, current_state, actions, noise,
            Wse, bse, Wae, bae, W1, b1, W2, b2, Wdec, bdec, Wunc, bunc, states);
    }
    reward_kernel<<<CBR, RH, 0, stream>>>(states, actions, Wr1, br1, Wr2, br2, Wr3, br3, cum);
    select_kernel<<<BB, 64, 0, stream>>>(cum, actions, (float*)d_out);
}